// Round 14
// baseline (34.211 us; speedup 1.0000x reference)
//
#include <hip/hip_runtime.h>

// PiecewiseHawkesIntensity — np-golden semantics (FROZEN since r11, passed):
//   inv = fl32(1/nc) (CR);  qn = fl32(q * inv)   [reciprocal-multiply key]
//   lo = searchsorted_LEFT(ev, qn); last = lo-1
//   i = clip(last,0); t_last = (last==-1)?0:ev[last]; dt = qn - t_last  (f32)
//   I = (mu_i + (alpha_i - mu_i)*exp(-beta_i*dt)) * inv
//
// r14 (scheduling only): 2 rows per barrier (16 barriers, was 32), double-
// buffered 2-row LDS stages, register prefetch issued one FULL 2-row sub-iter
// (~800+ cy) before its ds_write -> HBM latency covered. Named register trios
// (rule #20). Grid stays 256 x 1024 (1 block/CU, zero redundant work).

constexpr int B  = 16;
constexpr int M  = 32;
constexpr int P  = 16;
constexpr int L  = 1024;
constexpr int LE = 2048;

__global__ __launch_bounds__(1024)
void hawkes_kernel(const float* __restrict__ qt,   // [B,P,LE]
                   const float* __restrict__ ev,   // [B,P,L]
                   const float* __restrict__ mu,   // [B,M,P,L]
                   const float* __restrict__ al,   // [B,M,P,L]
                   const float* __restrict__ be,   // [B,M,P,L]
                   const float* __restrict__ nc,   // [B]
                   float* __restrict__ out)        // [B,M,P,LE]
{
    __shared__ float s_ev[L];
    __shared__ float s_mu[2][2][L];   // [buf][row-in-pair][idx]
    __shared__ float s_al[2][2][L];
    __shared__ float s_be[2][2][L];

    const int bp = blockIdx.x;          // 0..255  -> (b,p)
    const int b  = bp >> 4;
    const int p  = bp & (P - 1);
    const int t  = threadIdx.x;         // 0..1023

    const float norm     = nc[b];
    const float inv_norm = (float)(1.0 / (double)norm);   // CR f32 recip

    const size_t row0 = ((size_t)b * M * P + p) * L;   // [b,0,p,0]
    const size_t mstr = (size_t)P * L;                 // m-stride (16384)

    // prologue: ev row + param rows 0..3 issued together (independent loads)
    const float e_in = ev[(size_t)bp * L + t];
    float RA_mu0 = mu[row0 + t],            RA_al0 = al[row0 + t],            RA_be0 = be[row0 + t];
    float RA_mu1 = mu[row0 + mstr + t],     RA_al1 = al[row0 + mstr + t],     RA_be1 = be[row0 + mstr + t];
    float RB_mu0 = mu[row0 + 2 * mstr + t], RB_al0 = al[row0 + 2 * mstr + t], RB_be0 = be[row0 + 2 * mstr + t];
    float RB_mu1 = mu[row0 + 3 * mstr + t], RB_al1 = al[row0 + 3 * mstr + t], RB_be1 = be[row0 + 3 * mstr + t];

    s_ev[t] = e_in;
    s_mu[0][0][t] = RA_mu0;  s_al[0][0][t] = RA_al0;  s_be[0][0][t] = RA_be0;  // buf0 = rows 0,1
    s_mu[0][1][t] = RA_mu1;  s_al[0][1][t] = RA_al1;  s_be[0][1][t] = RA_be1;

    __syncthreads();   // s_ev + buf0 visible (RB_* still in flight)

    // two ADJACENT queries per thread (float2 I/O), fixed-trip interleaved search
    const float2 q2 = *reinterpret_cast<const float2*>(qt + (size_t)bp * LE + 2 * t);
    int   idx0, idx1;
    float dt0, dt1;
    {
        float qn[2] = { __fmul_rn(q2.x, inv_norm), __fmul_rn(q2.y, inv_norm) };
        int lo[2] = {0, 0}, hi[2] = {L, L};
#pragma unroll
        for (int s = 0; s < 11; ++s) {     // max path length over 1025 answers
#pragma unroll
            for (int k = 0; k < 2; ++k) {
                if (lo[k] < hi[k]) {       // guard: converged lanes stay put
                    const int mid = (lo[k] + hi[k]) >> 1;
                    if (s_ev[mid] < qn[k]) lo[k] = mid + 1; else hi[k] = mid;
                }
            }
        }
        const int l0 = lo[0] - 1, l1 = lo[1] - 1;
        idx0 = (l0 < 0) ? 0 : l0;   dt0 = qn[0] - ((l0 < 0) ? 0.0f : s_ev[idx0]);
        idx1 = (l1 < 0) ? 0 : l1;   dt1 = qn[1] - ((l1 < 0) ? 0.0f : s_ev[idx1]);
    }

    float* const obase = out + ((size_t)b * M * P + p) * LE + 2 * t;
    const size_t ostr  = (size_t)P * LE;   // out m-stride (32768)

#define COMPUTE_ROW(BUF, ROW, mrow)                                            \
    {                                                                          \
        float2 o;                                                              \
        {                                                                      \
            const float m0 = s_mu[BUF][ROW][idx0];                             \
            const float a0 = s_al[BUF][ROW][idx0];                             \
            const float b0 = s_be[BUF][ROW][idx0];                             \
            o.x = fmaf(a0 - m0, __expf(-b0 * dt0), m0) * inv_norm;             \
        }                                                                      \
        {                                                                      \
            const float m1 = s_mu[BUF][ROW][idx1];                             \
            const float a1 = s_al[BUF][ROW][idx1];                             \
            const float b1 = s_be[BUF][ROW][idx1];                             \
            o.y = fmaf(a1 - m1, __expf(-b1 * dt1), m1) * inv_norm;             \
        }                                                                      \
        *reinterpret_cast<float2*>(obase + (size_t)(mrow) * ostr) = o;         \
    }

#pragma unroll 1
    for (int j = 0; j < 8; ++j) {
        const int base = 4 * j;
        // ---- sub-iter A: compute rows base,base+1 from buf0 ----------------
        if (base + 4 < M) {       // RA regs free (flushed to buf0 last B / prologue)
            const size_t r4 = row0 + (size_t)(base + 4) * mstr;
            const size_t r5 = row0 + (size_t)(base + 5) * mstr;
            RA_mu0 = mu[r4 + t];  RA_al0 = al[r4 + t];  RA_be0 = be[r4 + t];
            RA_mu1 = mu[r5 + t];  RA_al1 = al[r5 + t];  RA_be1 = be[r5 + t];
        }
        COMPUTE_ROW(0, 0, base)
        COMPUTE_ROW(0, 1, base + 1)
        // stage rows base+2,base+3 (RB, issued one full sub-iter ago) into buf1
        s_mu[1][0][t] = RB_mu0;  s_al[1][0][t] = RB_al0;  s_be[1][0][t] = RB_be0;
        s_mu[1][1][t] = RB_mu1;  s_al[1][1][t] = RB_al1;  s_be[1][1][t] = RB_be1;
        __syncthreads();   // buf1 visible; all readers of buf0 done

        // ---- sub-iter B: compute rows base+2,base+3 from buf1 --------------
        if (base + 6 < M) {       // RB regs free (flushed to buf1 above)
            const size_t r6 = row0 + (size_t)(base + 6) * mstr;
            const size_t r7 = row0 + (size_t)(base + 7) * mstr;
            RB_mu0 = mu[r6 + t];  RB_al0 = al[r6 + t];  RB_be0 = be[r6 + t];
            RB_mu1 = mu[r7 + t];  RB_al1 = al[r7 + t];  RB_be1 = be[r7 + t];
        }
        COMPUTE_ROW(1, 0, base + 2)
        COMPUTE_ROW(1, 1, base + 3)
        // stage rows base+4,base+5 (RA) into buf0 for next iteration's A
        if (base + 4 < M) {
            s_mu[0][0][t] = RA_mu0;  s_al[0][0][t] = RA_al0;  s_be[0][0][t] = RA_be0;
            s_mu[0][1][t] = RA_mu1;  s_al[0][1][t] = RA_al1;  s_be[0][1][t] = RA_be1;
        }
        __syncthreads();   // buf0 visible; all readers of buf1 done
    }
#undef COMPUTE_ROW
}

extern "C" void kernel_launch(void* const* d_in, const int* in_sizes, int n_in,
                              void* d_out, int out_size, void* d_ws, size_t ws_size,
                              hipStream_t stream) {
    const float* qt = (const float*)d_in[0];
    const float* ev = (const float*)d_in[1];
    const float* mu = (const float*)d_in[2];
    const float* al = (const float*)d_in[3];
    const float* be = (const float*)d_in[4];
    const float* nc = (const float*)d_in[5];
    float* out = (float*)d_out;

    hawkes_kernel<<<B * P, 1024, 0, stream>>>(qt, ev, mu, al, be, nc, out);
}

// Round 15
// 33.831 us; speedup vs baseline: 1.0112x; 1.0112x over previous
//
#include <hip/hip_runtime.h>

// PiecewiseHawkesIntensity — np-golden semantics (FROZEN since r11, passed):
//   inv = fl32(1/nc) (CR);  qn = fl32(q * inv)   [reciprocal-multiply key]
//   lo = searchsorted_LEFT(ev, qn); last = lo-1
//   i = clip(last,0); t_last = (last==-1)?0:ev[last]; dt = qn - t_last  (f32)
//   I = (mu_i + (alpha_i - mu_i)*exp(-beta_i*dt)) * inv
//
// r15 (scheduling only): params packed {mu,al,be,pad} in ONE float4 LDS array.
// Gathers: 3x ds_read_b32 -> 1x aligned ds_read_b128 per (q,m) (192 -> 64
// instr/thread); staging: 3x b32 -> 1x contiguous b128 write. LDS pipe is the
// measured critical resource (~15.5us/CU of ~33us: 5.0M conflict cycles + base
// ~18K cy/CU) — r12/r13/r14 showed barriers/latency are NOT dominant.
// Skeleton = r13 (best, 33.2us): 1-row double-buffer, T14 register prefetch.

constexpr int B  = 16;
constexpr int M  = 32;
constexpr int P  = 16;
constexpr int L  = 1024;
constexpr int LE = 2048;

__global__ __launch_bounds__(1024)
void hawkes_kernel(const float* __restrict__ qt,   // [B,P,LE]
                   const float* __restrict__ ev,   // [B,P,L]
                   const float* __restrict__ mu,   // [B,M,P,L]
                   const float* __restrict__ al,   // [B,M,P,L]
                   const float* __restrict__ be,   // [B,M,P,L]
                   const float* __restrict__ nc,   // [B]
                   float* __restrict__ out)        // [B,M,P,LE]
{
    __shared__ float  s_ev[L];
    __shared__ float4 s_prm[2][L];    // {mu, al, be, pad} per event index

    const int bp = blockIdx.x;          // 0..255  -> (b,p)
    const int b  = bp >> 4;
    const int p  = bp & (P - 1);
    const int t  = threadIdx.x;         // 0..1023

    const float norm     = nc[b];
    const float inv_norm = (float)(1.0 / (double)norm);   // CR f32 recip

    const size_t row0 = ((size_t)b * M * P + p) * L;   // [b,0,p,0]
    const size_t mstr = (size_t)P * L;                 // m-stride

    // prologue: ev row + param rows 0,1 issued together (independent loads)
    const float e_in = ev[(size_t)bp * L + t];
    float rA_mu = mu[row0 + t],        rA_al = al[row0 + t],        rA_be = be[row0 + t];
    float rB_mu = mu[row0 + mstr + t], rB_al = al[row0 + mstr + t], rB_be = be[row0 + mstr + t];

    s_ev[t]     = e_in;
    s_prm[0][t] = make_float4(rA_mu, rA_al, rA_be, 0.0f);   // buf0 = row 0

    __syncthreads();   // s_ev + buf0 visible (rB_* still in flight)

    // two ADJACENT queries per thread (float2 I/O), fixed-trip interleaved search
    const float2 q2 = *reinterpret_cast<const float2*>(qt + (size_t)bp * LE + 2 * t);
    int   idx0, idx1;
    float dt0, dt1;
    {
        float qn[2] = { __fmul_rn(q2.x, inv_norm), __fmul_rn(q2.y, inv_norm) };
        int lo[2] = {0, 0}, hi[2] = {L, L};
#pragma unroll
        for (int s = 0; s < 11; ++s) {     // max path length over 1025 answers
#pragma unroll
            for (int k = 0; k < 2; ++k) {
                if (lo[k] < hi[k]) {       // guard: converged lanes stay put
                    const int mid = (lo[k] + hi[k]) >> 1;
                    if (s_ev[mid] < qn[k]) lo[k] = mid + 1; else hi[k] = mid;
                }
            }
        }
        const int l0 = lo[0] - 1, l1 = lo[1] - 1;
        idx0 = (l0 < 0) ? 0 : l0;   dt0 = qn[0] - ((l0 < 0) ? 0.0f : s_ev[idx0]);
        idx1 = (l1 < 0) ? 0 : l1;   dt1 = qn[1] - ((l1 < 0) ? 0.0f : s_ev[idx1]);
    }

    float* const obase = out + ((size_t)b * M * P + p) * LE + 2 * t;
    const size_t ostr  = (size_t)P * LE;   // out m-stride

#define COMPUTE_ROW(BUF, mrow)                                                  \
    {                                                                           \
        const float4 v0 = s_prm[BUF][idx0];                                     \
        const float4 v1 = s_prm[BUF][idx1];                                     \
        float2 o;                                                               \
        o.x = fmaf(v0.y - v0.x, __expf(-v0.z * dt0), v0.x) * inv_norm;          \
        o.y = fmaf(v1.y - v1.x, __expf(-v1.z * dt1), v1.x) * inv_norm;          \
        *reinterpret_cast<float2*>(obase + (size_t)(mrow) * ostr) = o;          \
    }

#pragma unroll 1
    for (int m = 0; m < M; m += 2) {
        // ---- sub-iter A: compute row m from buf0; rA regs free -> row m+2
        if (m + 2 < M) {
            const size_t r = row0 + (size_t)(m + 2) * mstr;
            rA_mu = mu[r + t];  rA_al = al[r + t];  rA_be = be[r + t];
        }
        COMPUTE_ROW(0, m)
        // stage row m+1 (rB, issued one full sub-iter ago) into buf1
        s_prm[1][t] = make_float4(rB_mu, rB_al, rB_be, 0.0f);
        __syncthreads();   // buf1 visible; all readers of buf0 done

        // ---- sub-iter B: compute row m+1 from buf1; rB regs free -> row m+3
        if (m + 3 < M) {
            const size_t r = row0 + (size_t)(m + 3) * mstr;
            rB_mu = mu[r + t];  rB_al = al[r + t];  rB_be = be[r + t];
        }
        COMPUTE_ROW(1, m + 1)
        // stage row m+2 (rA) into buf0
        if (m + 2 < M) {
            s_prm[0][t] = make_float4(rA_mu, rA_al, rA_be, 0.0f);
        }
        __syncthreads();   // buf0 visible; all readers of buf1 done
    }
#undef COMPUTE_ROW
}

extern "C" void kernel_launch(void* const* d_in, const int* in_sizes, int n_in,
                              void* d_out, int out_size, void* d_ws, size_t ws_size,
                              hipStream_t stream) {
    const float* qt = (const float*)d_in[0];
    const float* ev = (const float*)d_in[1];
    const float* mu = (const float*)d_in[2];
    const float* al = (const float*)d_in[3];
    const float* be = (const float*)d_in[4];
    const float* nc = (const float*)d_in[5];
    float* out = (float*)d_out;

    hawkes_kernel<<<B * P, 1024, 0, stream>>>(qt, ev, mu, al, be, nc, out);
}